// Round 1
// baseline (731.932 us; speedup 1.0000x reference)
//
#include <hip/hip_runtime.h>

#define NROWS  250000
#define DIM    512
#define TOPK   11        // 1 + K from reference top_k
#define KNEIGH 9         // idx[1:K] with K=10 -> 9 neighbors (reference slice)
#define NCLS   100
#define NB     1024      // stage-1 blocks
#define TPB    256
#define WPB    4         // waves per block
#define NWAVES (NB * WPB)
#define RPW    ((NROWS + NWAVES - 1) / NWAVES)   // rows per wave = 62
#define NC     (NB * TOPK)                       // stage-2 candidates = 11264

__device__ __forceinline__ bool better(float v1, int i1, float v2, int i2) {
    // lax.top_k order: value descending, index ascending on ties
    return (v1 > v2) || ((v1 == v2) && (i1 < i2));
}

__global__ __launch_bounds__(TPB) void knn_stage1(
    const float* __restrict__ emb,
    const float* __restrict__ coll,
    float* __restrict__ cand_v,
    int*   __restrict__ cand_i)
{
    const int lane = threadIdx.x & 63;
    const int warp = threadIdx.x >> 6;
    const int wid  = blockIdx.x * WPB + warp;

    // embedding fragment: lane covers e[lane*8 .. lane*8+8)
    const float4 e0 = *(const float4*)(emb + lane * 8);
    const float4 e1 = *(const float4*)(emb + lane * 8 + 4);
    float es = e0.x*e0.x + e0.y*e0.y + e0.z*e0.z + e0.w*e0.w
             + e1.x*e1.x + e1.y*e1.y + e1.z*e1.z + e1.w*e1.w;
    #pragma unroll
    for (int s = 1; s < 64; s <<= 1) es += __shfl_xor(es, s, 64);
    const float edenom = sqrtf(es + 1e-12f);

    float tv[TOPK];
    int   ti[TOPK];
    #pragma unroll
    for (int j = 0; j < TOPK; ++j) { tv[j] = -__builtin_inff(); ti[j] = 0x7fffffff; }

    const int row0 = wid * RPW;
    for (int r = 0; r < RPW; ++r) {
        const int row = row0 + r;
        if (row >= NROWS) break;
        const float* p = coll + (size_t)row * DIM + lane * 8;
        const float4 c0 = *(const float4*)p;
        const float4 c1 = *(const float4*)(p + 4);
        float dot = c0.x*e0.x + c0.y*e0.y + c0.z*e0.z + c0.w*e0.w
                  + c1.x*e1.x + c1.y*e1.y + c1.z*e1.z + c1.w*e1.w;
        float nrm = c0.x*c0.x + c0.y*c0.y + c0.z*c0.z + c0.w*c0.w
                  + c1.x*c1.x + c1.y*c1.y + c1.z*c1.z + c1.w*c1.w;
        #pragma unroll
        for (int s = 1; s < 64; s <<= 1) {
            dot += __shfl_xor(dot, s, 64);
            nrm += __shfl_xor(nrm, s, 64);
        }
        const float sim = dot / (sqrtf(nrm + 1e-12f) * edenom);
        // all lanes hold identical sim -> wave-uniform replicated top-11 insert
        if (better(sim, row, tv[TOPK-1], ti[TOPK-1])) {
            tv[TOPK-1] = sim; ti[TOPK-1] = row;
            #pragma unroll
            for (int j = TOPK-1; j > 0; --j) {
                if (better(tv[j], ti[j], tv[j-1], ti[j-1])) {
                    float fv = tv[j]; tv[j] = tv[j-1]; tv[j-1] = fv;
                    int   fi = ti[j]; ti[j] = ti[j-1]; ti[j-1] = fi;
                } else break;
            }
        }
    }

    // merge 4 wave-local top-11 lists -> block top-11
    __shared__ float sv[WPB * TOPK];
    __shared__ int   si[WPB * TOPK];
    if (lane == 0) {
        #pragma unroll
        for (int j = 0; j < TOPK; ++j) { sv[warp*TOPK + j] = tv[j]; si[warp*TOPK + j] = ti[j]; }
    }
    __syncthreads();
    if (warp == 0) {
        float v = (lane < WPB*TOPK) ? sv[lane] : -__builtin_inff();
        int   i = (lane < WPB*TOPK) ? si[lane] : 0x7fffffff;
        for (int r = 0; r < TOPK; ++r) {
            float bv = v; int bi = i;
            #pragma unroll
            for (int s = 1; s < 64; s <<= 1) {
                float ov = __shfl_xor(bv, s, 64);
                int   oi = __shfl_xor(bi, s, 64);
                if (better(ov, oi, bv, bi)) { bv = ov; bi = oi; }
            }
            if (v == bv && i == bi) v = -__builtin_inff();  // row indices unique -> one holder
            if (lane == 0) { cand_v[blockIdx.x*TOPK + r] = bv; cand_i[blockIdx.x*TOPK + r] = bi; }
        }
    }
}

__global__ __launch_bounds__(TPB) void knn_stage2(
    const float* __restrict__ cand_v,
    const int*   __restrict__ cand_i,
    const int*   __restrict__ labels,
    float* __restrict__ out)
{
    const int tid  = threadIdx.x;
    const int lane = tid & 63;
    const int warp = tid >> 6;

    // per-thread sorted top-11 over strided candidate subset (+1 pad slot for head ptr)
    float tv[TOPK + 1];
    int   ti[TOPK + 1];
    #pragma unroll
    for (int j = 0; j < TOPK + 1; ++j) { tv[j] = -__builtin_inff(); ti[j] = 0x7fffffff; }

    for (int j = tid; j < NC; j += TPB) {
        float v = cand_v[j]; int i = cand_i[j];
        if (better(v, i, tv[TOPK-1], ti[TOPK-1])) {
            tv[TOPK-1] = v; ti[TOPK-1] = i;
            #pragma unroll
            for (int q = TOPK-1; q > 0; --q) {
                if (better(tv[q], ti[q], tv[q-1], ti[q-1])) {
                    float fv = tv[q]; tv[q] = tv[q-1]; tv[q-1] = fv;
                    int   fi = ti[q]; ti[q] = ti[q-1]; ti[q-1] = fi;
                } else break;
            }
        }
    }

    __shared__ float lv[TPB * (TOPK + 1)];
    __shared__ int   li[TPB * (TOPK + 1)];
    #pragma unroll
    for (int j = 0; j < TOPK + 1; ++j) {
        lv[tid*(TOPK+1) + j] = tv[j];
        li[tid*(TOPK+1) + j] = ti[j];
    }

    __shared__ float rv[TOPK];
    __shared__ int   ri[TOPK];
    __shared__ float wv_[TPB/64];
    __shared__ int   wi_[TPB/64], wt_[TPB/64];
    __shared__ int   winner;
    __syncthreads();

    // k-way merge: each thread's list is sorted; 11 rounds of argmax over heads
    int p = 0;
    for (int r = 0; r < TOPK; ++r) {
        float cv = lv[tid*(TOPK+1) + p];
        int   ci = li[tid*(TOPK+1) + p];
        int   ct = tid;
        #pragma unroll
        for (int s = 1; s < 64; s <<= 1) {
            float ov = __shfl_xor(cv, s, 64);
            int   oi = __shfl_xor(ci, s, 64);
            int   ot = __shfl_xor(ct, s, 64);
            if (better(ov, oi, cv, ci)) { cv = ov; ci = oi; ct = ot; }
        }
        if (lane == 0) { wv_[warp] = cv; wi_[warp] = ci; wt_[warp] = ct; }
        __syncthreads();
        if (tid == 0) {
            float bv = wv_[0]; int bi = wi_[0]; int bt = wt_[0];
            for (int w = 1; w < TPB/64; ++w)
                if (better(wv_[w], wi_[w], bv, bi)) { bv = wv_[w]; bi = wi_[w]; bt = wt_[w]; }
            rv[r] = bv; ri[r] = bi; winner = bt;
        }
        __syncthreads();
        if (tid == winner) ++p;   // winner advances its sorted-list head
    }
    __syncthreads();

    if (tid == 0) {
        #pragma unroll
        for (int j = 0; j < TOPK; ++j) out[j] = rv[j];

        // vote over labels of idx[1:10] (9 neighbors, faithful to reference slice)
        int cnt[NCLS];
        for (int c = 0; c < NCLS; ++c) cnt[c] = 0;
        int preds[KNEIGH];
        for (int j = 0; j < KNEIGH; ++j) {
            preds[j] = labels[ri[1 + j]];
            ++cnt[preds[j]];
        }
        int best = 0, bc = cnt[0];
        for (int c = 1; c < NCLS; ++c) if (cnt[c] > bc) { bc = cnt[c]; best = c; }  // first max
        int cp = 0;
        for (int j = KNEIGH - 1; j >= 0; --j) if (preds[j] == best) cp = j;          // first match
        out[11] = (float)best;       // pred_int
        out[12] = rv[1 + cp];        // confidence = probs[conf_pos] = vals[1+conf_pos]
    }
}

extern "C" void kernel_launch(void* const* d_in, const int* in_sizes, int n_in,
                              void* d_out, int out_size, void* d_ws, size_t ws_size,
                              hipStream_t stream) {
    const float* emb    = (const float*)d_in[0];
    const float* coll   = (const float*)d_in[1];
    const int*   labels = (const int*)d_in[2];
    float*       out    = (float*)d_out;

    float* cand_v = (float*)d_ws;            // NC floats
    int*   cand_i = (int*)(cand_v + NC);     // NC ints  (total 90,112 B of ws)

    knn_stage1<<<NB, TPB, 0, stream>>>(emb, coll, cand_v, cand_i);
    knn_stage2<<<1, TPB, 0, stream>>>(cand_v, cand_i, labels, out);
}